// Round 15
// baseline (4352.393 us; speedup 1.0000x reference)
//
#include <hip/hip_runtime.h>
#include <math.h>

// Problem constants
#define NN   307
#define TT   256
#define HHH  64
#define NROW (NN*TT)     // 78592
#define NBLK_D 77        // ceil(307/4) blocks per direction
#define SCANB  154       // total scan blocks (2 directions)

// split-weight store offsets (elements)
#define OFF_O  (6*192*64)
#define OFF_F1 (OFF_O + 6*64*64)
#define OFF_F2 (OFF_F1 + 6*256*64)
#define NWTOT  (OFF_F2 + 6*64*256)

typedef unsigned short u16;
typedef __attribute__((ext_vector_type(8))) short short8;
typedef __attribute__((ext_vector_type(4))) float f4;

// ---------------- helpers ----------------
__device__ __forceinline__ float wsum(float v){
#pragma unroll
  for (int off = 32; off > 0; off >>= 1) v += __shfl_xor(v, off, 64);
  return v;
}
__device__ __forceinline__ float wsum16(float v){
#pragma unroll
  for (int off = 8; off > 0; off >>= 1) v += __shfl_xor(v, off, 64);
  return v;
}
__device__ __forceinline__ float ftanh(float x){
  x = fminf(20.f, fmaxf(-20.f, x));
  float e = __expf(2.f*x);
  return (e - 1.f)/(e + 1.f);
}
__device__ __forceinline__ float fsigm(float x){ return 1.f/(1.f + __expf(-x)); }

__device__ __forceinline__ u16 f2bf(float x){
  unsigned u = __float_as_uint(x);
  u += 0x7fffu + ((u >> 16) & 1u);
  return (u16)(u >> 16);
}
__device__ __forceinline__ float bf2f(u16 h){
  return __uint_as_float((unsigned)h << 16);
}
__device__ __forceinline__ void split8(const float* xv, short8& hi, short8& lo){
  union { short8 v; u16 u[8]; } H, L;
#pragma unroll
  for (int j = 0; j < 8; j++){
    const float x = xv[j];
    const u16 h = f2bf(x);
    H.u[j] = h;
    L.u[j] = f2bf(x - bf2f(h));
  }
  hi = H.v; lo = L.v;
}

// ---------------- prep kernels ----------------
__global__ void k_sparse(const float* __restrict__ A, int* __restrict__ cnt,
                         int* __restrict__ idx, float* __restrict__ val){
  int n = blockIdx.x*64 + threadIdx.x;
  if (n >= NN) return;
  int c = 0;
  for (int m = 0; m < NN; m++){
    float a = A[n*NN + m];
    if (a != 0.f){ idx[n*NN + c] = m; val[n*NN + c] = a; c++; }
  }
  cnt[n] = c;
}

__global__ void k_tr_cheb(const float* __restrict__ W0, const float* __restrict__ W1,
                          float* __restrict__ W0T, float* __restrict__ W1T){
  int t = blockIdx.x*256 + threadIdx.x;
  if (t >= 2*67*256) return;
  int c = t & 255; int rest = t >> 8; int i = rest % 67; int d = rest / 67;
  int p = c >> 6, o = c & 63;
  int src = ((d*4 + p)*64 + o)*67 + i;
  W0T[t] = W0[src];
  W1T[t] = W1[src];
}

__global__ void k_tr_gru(const float* __restrict__ Wih, const float* __restrict__ Whh,
                         float* __restrict__ WihT, float* __restrict__ WhhT){
  int t = blockIdx.x*256 + threadIdx.x;
  if (t < 2*66*192){
    int j = t % 192; int rest = t / 192; int i = rest % 66; int d = rest / 66;
    WihT[t] = Wih[(d*192 + j)*66 + i];
  }
  if (t < 2*64*192){
    int j = t % 192; int rest = t / 192; int i = rest % 64; int d = rest / 64;
    WhhT[t] = Whh[(d*192 + j)*64 + i];
  }
}

__global__ void k_af(const float* __restrict__ mseq, const float* __restrict__ tfr,
                     const float* __restrict__ tjm, const int* __restrict__ cnt,
                     const int* __restrict__ idx, const float* __restrict__ val,
                     float* __restrict__ AF){
  int n = blockIdx.x, c = blockIdx.y, t = threadIdx.x;
  const float* feat = (c == 0) ? mseq : (c == 1) ? tfr : tjm;
  float acc = 0.f; int k = cnt[n];
  for (int s = 0; s < k; s++) acc += val[n*NN + s] * feat[idx[n*NN + s]*TT + t];
  AF[((size_t)c*NN + n)*TT + t] = acc;
}

__global__ void k_split(const float* __restrict__ src, u16* __restrict__ hi,
                        u16* __restrict__ lo, int n){
  int i = blockIdx.x*256 + threadIdx.x;
  if (i >= n) return;
  const float x = src[i];
  const u16 h = f2bf(x);
  hi[i] = h;
  lo[i] = f2bf(x - bf2f(h));
}

// --- recurrent scan: DATAFLOW sync — poll only owner blocks of own neighbors.
// --- Hseq slots are write-once per step, so inter-block skew is unbounded-safe;
// --- jitter amortizes along dependency chains instead of per-step max-reduce.
__global__ __launch_bounds__(256, 1)
void k_scan(const float* __restrict__ xseq, const float* __restrict__ mseq,
            const float* __restrict__ tfr, const float* __restrict__ tjm,
            const float* __restrict__ W0T, const float* __restrict__ W1T,
            const float* __restrict__ b0g,
            const float* __restrict__ mixW, const float* __restrict__ mixb,
            const float* __restrict__ WihT, const float* __restrict__ WhhT,
            const float* __restrict__ bih, const float* __restrict__ bhh,
            const int* __restrict__ spcnt, const int* __restrict__ spidx,
            const float* __restrict__ spval, const float* __restrict__ AF,
            float* __restrict__ Hseq, int* __restrict__ slots)
{
  const int tid = threadIdx.x;
  const int bid = blockIdx.x;
  const int d   = bid / NBLK_D;
  const int n0  = (bid % NBLK_D) * 4;
  const int lane = tid & 63;
  const int wid  = tid >> 6;

  __shared__ __align__(16) float hsT[64][4];
  __shared__ __align__(16) float amsT[68][4];
  __shared__ __align__(16) float msgsT[64][4];
  __shared__ float malls[256][5];
  __shared__ float gis[4][192];
  __shared__ float ghs[4][192];
  __shared__ float mixs[4][4];
  __shared__ float xss[4], mss[4], tfs[4], tjs[4];
  __shared__ int   s_idx[4][320];
  __shared__ float s_val[4][320];
  __shared__ int   s_cnt[4];
  __shared__ int   s_need[NBLK_D];   // dependency mask over same-direction blocks

  float w0r[67], w1r[67];
#pragma unroll
  for (int i = 0; i < 67; i++){
    w0r[i] = W0T[(d*67 + i)*256 + tid];
    w1r[i] = W1T[(d*67 + i)*256 + tid];
  }
  const float b0r = b0g[d*256 + tid];
  float wih_r[64], whh_r[64];
  float wih64 = 0.f, wih65 = 0.f, bih_r = 0.f, bhh_r = 0.f;
  if (tid < 192){
#pragma unroll
    for (int i = 0; i < 64; i++){
      whh_r[i] = WhhT[(d*64 + i)*192 + tid];
      wih_r[i] = WihT[(d*66 + i)*192 + tid];
    }
    wih64 = WihT[(d*66 + 64)*192 + tid];
    wih65 = WihT[(d*66 + 65)*192 + tid];
    bih_r = bih[d*192 + tid];
    bhh_r = bhh[d*192 + tid];
  }
  float mixw_r[4];
#pragma unroll
  for (int p = 0; p < 4; p++) mixw_r[p] = mixW[(d*4 + p)*64 + lane];
  const float mixb0 = mixb[d*4+0], mixb1 = mixb[d*4+1], mixb2 = mixb[d*4+2], mixb3 = mixb[d*4+3];

  for (int i = tid; i < NBLK_D; i += 256) s_need[i] = 0;
  __syncthreads();
  for (int r = 0; r < 4; r++){
    const int n = min(n0 + r, NN-1);
    const int cc = spcnt[n];
    const int ccp = (cc + 15) & ~15;
    if (tid == 0) s_cnt[r] = ccp;
    for (int s = tid; s < ccp; s += 256){
      const int m = (s < cc) ? spidx[n*NN + s] : 0;
      s_idx[r][s] = m;
      s_val[r][s] = (s < cc) ? spval[n*NN + s] : 0.f;
      s_need[m >> 2] = 1;     // mark owner block (padding adds block 0: harmless)
    }
  }
  hsT[lane][wid] = 0.f;
  __syncthreads();
  // hoist per-lane dependency flags into registers
  const bool need0 = (lane < NBLK_D) && (s_need[lane] != 0);
  const bool need1 = (lane + 64 < NBLK_D) && (s_need[lane + 64] != 0);

#pragma unroll 1
  for (int k = 0; k < TT; k++){
    const int ts = (d == 0) ? k : (TT-1 - k);
    if (tid < 4){
      const int r = tid; const int n = min(n0 + r, NN-1);
      const float mv = mseq[n*TT + ts];
      mss[r] = mv; tfs[r] = tfr[n*TT + ts]; tjs[r] = tjm[n*TT + ts];
      xss[r] = xseq[n*TT + ts];
      amsT[64][r] = AF[(0*NN + n)*TT + ts];
      amsT[65][r] = AF[(1*NN + n)*TT + ts];
      amsT[66][r] = AF[(2*NN + n)*TT + ts];
    }
    {
      const int r = wid;
      const float hv = hsT[lane][r];
      float l0 = wsum(hv * mixw_r[0]) + mixb0;
      float l1 = wsum(hv * mixw_r[1]) + mixb1;
      float l2 = wsum(hv * mixw_r[2]) + mixb2;
      float l3 = wsum(hv * mixw_r[3]) + mixb3;
      const float mx = fmaxf(fmaxf(l0,l1), fmaxf(l2,l3));
      const float e0 = __expf(l0-mx), e1 = __expf(l1-mx), e2 = __expf(l2-mx), e3 = __expf(l3-mx);
      const float inv = 1.f/(e0+e1+e2+e3);
      if (lane == 0){
        mixs[0][r] = e0*inv; mixs[1][r] = e1*inv; mixs[2][r] = e2*inv; mixs[3][r] = e3*inv;
      }
    }
    __syncthreads();
    {
      float a0 = b0r, a1 = b0r, a2 = b0r, a3 = b0r;
#pragma unroll
      for (int i = 0; i < 64; i++){
        const float4 h4 = *(const float4*)&hsT[i][0];
        const float w = w0r[i];
        a0 += h4.x*w; a1 += h4.y*w; a2 += h4.z*w; a3 += h4.w*w;
      }
      a0 += mss[0]*w0r[64] + tfs[0]*w0r[65] + tjs[0]*w0r[66];
      a1 += mss[1]*w0r[64] + tfs[1]*w0r[65] + tjs[1]*w0r[66];
      a2 += mss[2]*w0r[64] + tfs[2]*w0r[65] + tjs[2]*w0r[66];
      a3 += mss[3]*w0r[64] + tfs[3]*w0r[65] + tjs[3]*w0r[66];
      malls[tid][0] = a0; malls[tid][1] = a1; malls[tid][2] = a2; malls[tid][3] = a3;
    }
    if (tid < 192){
      float g0 = bhh_r, g1 = bhh_r, g2 = bhh_r, g3 = bhh_r;
#pragma unroll
      for (int i = 0; i < 64; i++){
        const float4 h4 = *(const float4*)&hsT[i][0];
        const float w = whh_r[i];
        g0 += h4.x*w; g1 += h4.y*w; g2 += h4.z*w; g3 += h4.w*w;
      }
      ghs[0][tid] = g0; ghs[1][tid] = g1; ghs[2][tid] = g2; ghs[3][tid] = g3;
      gis[0][tid] = bih_r + (xss[0]*mss[0])*wih64 + mss[0]*wih65;
      gis[1][tid] = bih_r + (xss[1]*mss[1])*wih64 + mss[1]*wih65;
      gis[2][tid] = bih_r + (xss[2]*mss[2])*wih64 + mss[2]*wih65;
      gis[3][tid] = bih_r + (xss[3]*mss[3])*wih64 + mss[3]*wih65;
    }
    // ---- dataflow wait: only owner blocks of our neighbors, masked poll ----
    if (k > 0 && tid < 64){
      const int* sl = slots + (size_t)d*NBLK_D*16;
      for (;;){
        const int va = need0
            ? __hip_atomic_load(&sl[lane*16], __ATOMIC_RELAXED, __HIP_MEMORY_SCOPE_AGENT)
            : 0x7fffffff;
        const int vb = need1
            ? __hip_atomic_load(&sl[(lane+64)*16], __ATOMIC_RELAXED, __HIP_MEMORY_SCOPE_AGENT)
            : 0x7fffffff;
        if (__all(min(va, vb) >= k)) break;
        __builtin_amdgcn_s_sleep(1);
      }
    }
    __syncthreads();
    {
      const float* Hprev = Hseq + (size_t)(d*257 + k)*NN*64;
      const int r = wid;
      const int ccp = s_cnt[r];
      float acc = 0.f;
      for (int s = 0; s < ccp; s += 16){
        float aV[16], hV[16];
#pragma unroll
        for (int u = 0; u < 16; u++){
          const int m = s_idx[r][s+u];
          aV[u] = s_val[r][s+u];
          hV[u] = __hip_atomic_load(&Hprev[(size_t)m*64 + lane],
                                    __ATOMIC_RELAXED, __HIP_MEMORY_SCOPE_AGENT);
        }
#pragma unroll
        for (int u = 0; u < 16; u++) acc += aV[u]*hV[u];
      }
      amsT[lane][r] = acc;
    }
    __syncthreads();
    {
      const int p = tid >> 6;
      float pa0 = malls[tid][0], pa1 = malls[tid][1], pa2 = malls[tid][2], pa3 = malls[tid][3];
#pragma unroll
      for (int i = 0; i < 67; i++){
        const float4 m4 = *(const float4*)&amsT[i][0];
        const float w = w1r[i];
        pa0 += m4.x*w; pa1 += m4.y*w; pa2 += m4.z*w; pa3 += m4.w*w;
      }
      malls[tid][0] = mixs[p][0]*ftanh(pa0);
      malls[tid][1] = mixs[p][1]*ftanh(pa1);
      malls[tid][2] = mixs[p][2]*ftanh(pa2);
      malls[tid][3] = mixs[p][3]*ftanh(pa3);
    }
    __syncthreads();
    msgsT[lane][wid] = malls[lane][wid] + malls[64+lane][wid] + malls[128+lane][wid] + malls[192+lane][wid];
    __syncthreads();
    if (tid < 192){
      float q0 = gis[0][tid], q1 = gis[1][tid], q2 = gis[2][tid], q3 = gis[3][tid];
#pragma unroll
      for (int i = 0; i < 64; i++){
        const float4 m4 = *(const float4*)&msgsT[i][0];
        const float w = wih_r[i];
        q0 += m4.x*w; q1 += m4.y*w; q2 += m4.z*w; q3 += m4.w*w;
      }
      gis[0][tid] = q0; gis[1][tid] = q1; gis[2][tid] = q2; gis[3][tid] = q3;
    }
    __syncthreads();
    {
      const int r = wid, o = lane;
      const float ir = gis[r][o], iz = gis[r][o+64], in_ = gis[r][o+128];
      const float hr = ghs[r][o], hz = ghs[r][o+64], hn = ghs[r][o+128];
      const float rr2 = fsigm(ir + hr);
      const float zz = fsigm(iz + hz);
      const float nnv = ftanh(in_ + rr2*hn);
      const float hold = hsT[o][r];
      const float h2 = (1.f - zz)*nnv + zz*hold + 0.1f*hold;
      hsT[o][r] = h2;
      const int n = n0 + r;
      if (n < NN)
        __hip_atomic_store(&Hseq[((size_t)(d*257 + k + 1)*NN + n)*64 + o], h2,
                           __ATOMIC_RELAXED, __HIP_MEMORY_SCOPE_AGENT);
    }
    __syncthreads();
    if (tid == 0)
      __hip_atomic_store(&slots[bid*16], k + 1, __ATOMIC_RELAXED, __HIP_MEMORY_SCOPE_AGENT);
  }
}

// ---------------- fusion: pred/jam from Hseq + fuse weights + pos-enc ----------------
__global__ __launch_bounds__(256)
void k_fusion(const float* __restrict__ Hseq,
              const float* __restrict__ outW, const float* __restrict__ outb,
              const float* __restrict__ jamW, const float* __restrict__ jamb,
              const float* __restrict__ fw1, const float* __restrict__ fb1,
              const float* __restrict__ fw2, const float* __restrict__ fb2,
              float* __restrict__ x0, float* __restrict__ outp)
{
  const int tid = threadIdx.x;
  const int rr = tid >> 6, lane = tid & 63;
  const int idx = blockIdx.x*4 + rr;
  const int n = idx >> 8, t = idx & 255;
  const float hf = Hseq[((size_t)(0*257 + t + 1)*NN + n)*64 + lane];
  const float hb = Hseq[((size_t)(257 + 256 - t)*NN + n)*64 + lane];
  const float pf = wsum(hf * outW[lane])      + outb[0];
  const float pb = wsum(hb * outW[64 + lane]) + outb[1];
  const float jf = wsum(hf * jamW[lane])      + jamb[0];
  const float jb = wsum(hb * jamW[64 + lane]) + jamb[1];
  const float hid = fmaxf(fw1[lane*2]*pf + fw1[lane*2+1]*pb + fb1[lane], 0.f);
  const float l0 = wsum(hid * fw2[lane]) + fb2[0];
  const float l1 = wsum(hid * fw2[64+lane]) + fb2[1];
  const float mx = fmaxf(l0,l1);
  const float e0 = __expf(l0-mx), e1 = __expf(l1-mx);
  const float inv = 1.f/(e0+e1);
  const float w0 = e0*inv, w1 = e1*inv;
  const int i2 = lane & ~1;
  const float dv = powf(10000.f, (float)i2 * (1.f/64.f));
  const float arg = (float)t / dv;
  const float pe = (lane & 1) ? cosf(arg) : sinf(arg);
  x0[(size_t)idx*64 + lane] = hf*w0 + hb*w1 + pe;
  if (lane == 0){
    outp[idx]        = 0.7f*(w0*pf + w1*pb);
    outp[NROW + idx] = 0.7f*(w0*jf + w1*jb);
  }
}

// ------- fused qkv + attention: block=(node, e), wave=head -------
__global__ __launch_bounds__(256)
void k_qkattn(const float* __restrict__ X0, const float* __restrict__ XBUF, int lyr,
              const u16* __restrict__ WHI, const u16* __restrict__ WLO,
              const float* __restrict__ qkvb_all, float* __restrict__ OBUF)
{
  __shared__ __align__(16) u16 Xhi[256][72];
  __shared__ __align__(16) u16 Vt [4][16][280];
  __shared__ __align__(16) u16 Pst[4][16][264];
  __shared__ __align__(16) u16 Kscr[4][16][24];
  __shared__ __align__(16) u16 Qhs[4][16][24];
  __shared__ __align__(16) u16 Qls[4][16][24];
  const int n = blockIdx.x;
  const int e = blockIdx.y;
  const int el = e*3 + lyr;
  const float* X = (lyr == 0) ? X0 : (XBUF + (size_t)e*NROW*64);
  const u16* Whi = WHI + (size_t)el*192*64;
  const u16* Wlo = WLO + (size_t)el*192*64;
  const float* bias = qkvb_all + (size_t)el*192;
  float* O = OBUF + (size_t)e*NROW*64;
  const int tid = threadIdx.x;
  const int h = tid >> 6;
  const int l = tid & 63;
  const int m16 = l & 15, q = l >> 4;
  const float* xbase = X + (size_t)n*256*64;
  const short8 z8 = {0,0,0,0,0,0,0,0};

  {
    const float* xr = xbase + (size_t)tid*64;
#pragma unroll
    for (int c = 0; c < 64; c += 8){
      float v[8];
      *(float4*)&v[0] = *(const float4*)&xr[c];
      *(float4*)&v[4] = *(const float4*)&xr[c+4];
      union { short8 s; u16 u[8]; } pk;
#pragma unroll
      for (int j = 0; j < 8; j++) pk.u[j] = f2bf(v[j]);
      *(short8*)&Xhi[tid][c] = pk.s;
    }
  }
  __syncthreads();

  short8 WqH[2], WqL[2], WkH[2], WkL[2], WvH[2], WvL[2];
#pragma unroll
  for (int kh = 0; kh < 2; kh++){
    const size_t rq = (size_t)(h*16 + m16)*64 + kh*32 + q*8;
    const size_t rk = (size_t)(64 + h*16 + m16)*64 + kh*32 + q*8;
    const size_t rv = (size_t)(128 + h*16 + m16)*64 + kh*32 + q*8;
    WqH[kh] = *(const short8*)&Whi[rq]; WqL[kh] = *(const short8*)&Wlo[rq];
    WkH[kh] = *(const short8*)&Whi[rk]; WkL[kh] = *(const short8*)&Wlo[rk];
    WvH[kh] = *(const short8*)&Whi[rv]; WvL[kh] = *(const short8*)&Wlo[rv];
  }
  const float qb = bias[h*16 + m16];
  const float kb = bias[64 + h*16 + m16];
  const float vb = bias[128 + h*16 + m16];

  short8 Kb[16];
#pragma unroll 1
  for (int ct = 0; ct < 16; ct++){
    short8 Xa0 = *(const short8*)&Xhi[ct*16 + m16][q*8];
    short8 Xa1 = *(const short8*)&Xhi[ct*16 + m16][32 + q*8];
    f4 ka = {0.f,0.f,0.f,0.f}, va = {0.f,0.f,0.f,0.f};
    ka = __builtin_amdgcn_mfma_f32_16x16x32_bf16(Xa0, WkH[0], ka, 0, 0, 0);
    ka = __builtin_amdgcn_mfma_f32_16x16x32_bf16(Xa0, WkL[0], ka, 0, 0, 0);
    ka = __builtin_amdgcn_mfma_f32_16x16x32_bf16(Xa1, WkH[1], ka, 0, 0, 0);
    ka = __builtin_amdgcn_mfma_f32_16x16x32_bf16(Xa1, WkL[1], ka, 0, 0, 0);
    va = __builtin_amdgcn_mfma_f32_16x16x32_bf16(Xa0, WvH[0], va, 0, 0, 0);
    va = __builtin_amdgcn_mfma_f32_16x16x32_bf16(Xa0, WvL[0], va, 0, 0, 0);
    va = __builtin_amdgcn_mfma_f32_16x16x32_bf16(Xa1, WvH[1], va, 0, 0, 0);
    va = __builtin_amdgcn_mfma_f32_16x16x32_bf16(Xa1, WvL[1], va, 0, 0, 0);
#pragma unroll
    for (int r = 0; r < 4; r++){
      Kscr[h][q*4 + r][m16] = f2bf(ka[r] + kb);
      Vt[h][m16][ct*16 + q*4 + r] = f2bf(va[r] + vb);
    }
    Kb[ct] = (q < 2) ? *(const short8*)&Kscr[h][m16][q*8] : z8;
  }

#pragma unroll 1
  for (int c = 0; c < 16; c++){
    short8 Xa0 = *(const short8*)&Xhi[c*16 + m16][q*8];
    short8 Xa1 = *(const short8*)&Xhi[c*16 + m16][32 + q*8];
    f4 qa = {0.f,0.f,0.f,0.f};
    qa = __builtin_amdgcn_mfma_f32_16x16x32_bf16(Xa0, WqH[0], qa, 0, 0, 0);
    qa = __builtin_amdgcn_mfma_f32_16x16x32_bf16(Xa0, WqL[0], qa, 0, 0, 0);
    qa = __builtin_amdgcn_mfma_f32_16x16x32_bf16(Xa1, WqH[1], qa, 0, 0, 0);
    qa = __builtin_amdgcn_mfma_f32_16x16x32_bf16(Xa1, WqL[1], qa, 0, 0, 0);
#pragma unroll
    for (int r = 0; r < 4; r++){
      const float qv = (qa[r] + qb) * 0.25f;
      const u16 hh = f2bf(qv);
      Qhs[h][q*4 + r][m16] = hh;
      Qls[h][q*4 + r][m16] = f2bf(qv - bf2f(hh));
    }
    short8 Qh = z8, Ql = z8;
    if (q < 2){
      Qh = *(const short8*)&Qhs[h][m16][q*8];
      Ql = *(const short8*)&Qls[h][m16][q*8];
    }
    float rs[4] = {0.f, 0.f, 0.f, 0.f};
#pragma unroll
    for (int ct = 0; ct < 16; ct++){
      f4 s = {0.f,0.f,0.f,0.f};
      s = __builtin_amdgcn_mfma_f32_16x16x32_bf16(Qh, Kb[ct], s, 0, 0, 0);
      s = __builtin_amdgcn_mfma_f32_16x16x32_bf16(Ql, Kb[ct], s, 0, 0, 0);
#pragma unroll
      for (int r = 0; r < 4; r++){
        const float p = __expf(s[r]);
        rs[r] += p;
        Pst[h][q*4 + r][ct*16 + m16] = f2bf(p);
      }
    }
#pragma unroll
    for (int r = 0; r < 4; r++) rs[r] = wsum16(rs[r]);
    f4 acc = {0.f,0.f,0.f,0.f};
#pragma unroll
    for (int kt = 0; kt < 8; kt++){
      const short8 Pa = *(const short8*)&Pst[h][m16][kt*32 + q*8];
      const short8 Vb = *(const short8*)&Vt[h][m16][kt*32 + q*8];
      acc = __builtin_amdgcn_mfma_f32_16x16x32_bf16(Pa, Vb, acc, 0, 0, 0);
    }
#pragma unroll
    for (int r = 0; r < 4; r++){
      O[((size_t)n*256 + c*16 + q*4 + r)*64 + h*16 + m16] = acc[r] / rs[r];
    }
  }
}

// ------- oproj + residual + LN1: block=(tile, e) -------
__global__ __launch_bounds__(256)
void k_oproj_ln(const float* __restrict__ OBUF, const float* __restrict__ X0,
                float* __restrict__ XBUF, int lyr,
                const u16* __restrict__ WHI, const u16* __restrict__ WLO,
                const float* __restrict__ ob_all,
                const float* __restrict__ g_all, const float* __restrict__ b_all)
{
  const int e = blockIdx.y;
  const int el = e*3 + lyr;
  const float* X = OBUF + (size_t)e*NROW*64;
  const float* Xres = (lyr == 0) ? X0 : (XBUF + (size_t)e*NROW*64);
  float* Y = XBUF + (size_t)e*NROW*64;
  const u16* Whi = WHI + OFF_O + (size_t)el*64*64;
  const u16* Wlo = WLO + OFF_O + (size_t)el*64*64;
  const float* bias = ob_all + (size_t)el*64;
  const float* g = g_all + (size_t)el*64;
  const float* b = b_all + (size_t)el*64;
  const int tid = threadIdx.x;
  const int w = tid >> 6, l = tid & 63;
  const int m16 = l & 15, q = l >> 4;
  const int row = blockIdx.x*64 + w*16 + m16;
  short8 Ah[2], Al[2];
#pragma unroll
  for (int kh = 0; kh < 2; kh++){
    float xv[8];
    *(float4*)&xv[0] = *(const float4*)&X[(size_t)row*64 + kh*32 + q*8];
    *(float4*)&xv[4] = *(const float4*)&X[(size_t)row*64 + kh*32 + q*8 + 4];
    split8(xv, Ah[kh], Al[kh]);
  }
  f4 acc[4];
#pragma unroll
  for (int nt = 0; nt < 4; nt++){
    acc[nt] = (f4){0.f, 0.f, 0.f, 0.f};
    const int n = nt*16 + m16;
#pragma unroll
    for (int kh = 0; kh < 2; kh++){
      const short8 Bh = *(const short8*)&Whi[(size_t)n*64 + kh*32 + q*8];
      const short8 Bl = *(const short8*)&Wlo[(size_t)n*64 + kh*32 + q*8];
      acc[nt] = __builtin_amdgcn_mfma_f32_16x16x32_bf16(Ah[kh], Bh, acc[nt], 0, 0, 0);
      acc[nt] = __builtin_amdgcn_mfma_f32_16x16x32_bf16(Ah[kh], Bl, acc[nt], 0, 0, 0);
      acc[nt] = __builtin_amdgcn_mfma_f32_16x16x32_bf16(Al[kh], Bh, acc[nt], 0, 0, 0);
    }
  }
  const int rbase = blockIdx.x*64 + w*16 + q*4;
#pragma unroll
  for (int r = 0; r < 4; r++){
    float v[4]; float s = 0.f;
#pragma unroll
    for (int nt = 0; nt < 4; nt++){
      const int col = nt*16 + m16;
      v[nt] = acc[nt][r] + bias[col] + Xres[(size_t)(rbase + r)*64 + col];
      s += v[nt];
    }
    const float mu = wsum16(s) * (1.f/64.f);
    float vs = 0.f;
#pragma unroll
    for (int nt = 0; nt < 4; nt++){ v[nt] -= mu; vs += v[nt]*v[nt]; }
    const float rstd = rsqrtf(wsum16(vs) * (1.f/64.f) + 1e-5f);
#pragma unroll
    for (int nt = 0; nt < 4; nt++){
      const int col = nt*16 + m16;
      Y[(size_t)(rbase + r)*64 + col] = v[nt] * rstd * g[col] + b[col];
    }
  }
}

// ------- fused FF block: block=(tile, e), in-place on XBUF -------
__global__ __launch_bounds__(256)
void k_ffblock(float* __restrict__ XBUF, int lyr,
               const u16* __restrict__ WHI, const u16* __restrict__ WLO,
               const float* __restrict__ b1_all, const float* __restrict__ b2_all,
               const float* __restrict__ g_all, const float* __restrict__ b_all)
{
  __shared__ __align__(16) u16 Hs[64][280];
  const int e = blockIdx.y;
  const int el = e*3 + lyr;
  float* X = XBUF + (size_t)e*NROW*64;
  const u16* W1hi = WHI + OFF_F1 + (size_t)el*256*64;
  const u16* W1lo = WLO + OFF_F1 + (size_t)el*256*64;
  const u16* W2hi = WHI + OFF_F2 + (size_t)el*64*256;
  const u16* W2lo = WLO + OFF_F2 + (size_t)el*64*256;
  const float* b1 = b1_all + (size_t)el*256;
  const float* b2 = b2_all + (size_t)el*64;
  const float* g = g_all + (size_t)el*64;
  const float* b = b_all + (size_t)el*64;
  const int tid = threadIdx.x;
  const int w = tid >> 6, l = tid & 63;
  const int m16 = l & 15, q = l >> 4;
  const int row = blockIdx.x*64 + w*16 + m16;
  short8 Ah[2], Al[2];
#pragma unroll
  for (int kh = 0; kh < 2; kh++){
    float xv[8];
    *(float4*)&xv[0] = *(const float4*)&X[(size_t)row*64 + kh*32 + q*8];
    *(float4*)&xv[4] = *(const float4*)&X[(size_t)row*64 + kh*32 + q*8 + 4];
    split8(xv, Ah[kh], Al[kh]);
  }
  for (int nt = 0; nt < 16; nt++){
    const int n = nt*16 + m16;
    f4 acc = {0.f, 0.f, 0.f, 0.f};
#pragma unroll
    for (int kh = 0; kh < 2; kh++){
      const short8 Bh = *(const short8*)&W1hi[(size_t)n*64 + kh*32 + q*8];
      const short8 Bl = *(const short8*)&W1lo[(size_t)n*64 + kh*32 + q*8];
      acc = __builtin_amdgcn_mfma_f32_16x16x32_bf16(Ah[kh], Bh, acc, 0, 0, 0);
      acc = __builtin_amdgcn_mfma_f32_16x16x32_bf16(Ah[kh], Bl, acc, 0, 0, 0);
      acc = __builtin_amdgcn_mfma_f32_16x16x32_bf16(Al[kh], Bh, acc, 0, 0, 0);
    }
    const float bb = b1[n];
#pragma unroll
    for (int r = 0; r < 4; r++){
      const float h = fmaxf(acc[r] + bb, 0.f);
      Hs[w*16 + q*4 + r][n] = f2bf(h);
    }
  }
  __syncthreads();
  f4 acc2[4];
#pragma unroll
  for (int nt = 0; nt < 4; nt++) acc2[nt] = (f4){0.f, 0.f, 0.f, 0.f};
#pragma unroll 1
  for (int kh = 0; kh < 8; kh++){
    const short8 Ahh = *(const short8*)&Hs[w*16 + m16][kh*32 + q*8];
#pragma unroll
    for (int nt = 0; nt < 4; nt++){
      const int n = nt*16 + m16;
      const short8 Bh = *(const short8*)&W2hi[(size_t)n*256 + kh*32 + q*8];
      const short8 Bl = *(const short8*)&W2lo[(size_t)n*256 + kh*32 + q*8];
      acc2[nt] = __builtin_amdgcn_mfma_f32_16x16x32_bf16(Ahh, Bh, acc2[nt], 0, 0, 0);
      acc2[nt] = __builtin_amdgcn_mfma_f32_16x16x32_bf16(Ahh, Bl, acc2[nt], 0, 0, 0);
    }
  }
  const int rbase = blockIdx.x*64 + w*16 + q*4;
#pragma unroll
  for (int r = 0; r < 4; r++){
    float v[4]; float s = 0.f;
#pragma unroll
    for (int nt = 0; nt < 4; nt++){
      const int col = nt*16 + m16;
      v[nt] = acc2[nt][r] + b2[col] + X[(size_t)(rbase + r)*64 + col];
      s += v[nt];
    }
    const float mu = wsum16(s) * (1.f/64.f);
    float vs = 0.f;
#pragma unroll
    for (int nt = 0; nt < 4; nt++){ v[nt] -= mu; vs += v[nt]*v[nt]; }
    const float rstd = rsqrtf(wsum16(vs) * (1.f/64.f) + 1e-5f);
#pragma unroll
    for (int nt = 0; nt < 4; nt++){
      const int col = nt*16 + m16;
      X[(size_t)(rbase + r)*64 + col] = v[nt] * rstd * g[col] + b[col];
    }
  }
}

// ---------------- final projection: block=(tile, e) ----------------
__global__ __launch_bounds__(256)
void k_proj_add(const float* __restrict__ XBUF, const float* __restrict__ prW,
                const float* __restrict__ prb, float* __restrict__ out)
{
  const int e = blockIdx.y;
  const float* X = XBUF + (size_t)e*NROW*64;
  const float* pW = prW + (size_t)e*64;
  float* outp = out + (size_t)e*NROW;
  const int tid = threadIdx.x;
  const int r = tid >> 6, lane = tid & 63;
  const size_t row = (size_t)blockIdx.x*4 + r;
  const float v = X[row*64 + lane] * pW[lane];
  const float s = wsum(v);
  if (lane == 0) outp[row] += 0.3f*(s + prb[e]);
}

// ---------------- host launcher ----------------
extern "C" void kernel_launch(void* const* d_in, const int* in_sizes, int n_in,
                              void* d_out, int out_size, void* d_ws, size_t ws_size,
                              hipStream_t stream)
{
  const float* x_seq = (const float*)d_in[0];
  const float* m_seq = (const float*)d_in[1];
  const float* tod_f = (const float*)d_in[2];
  const float* tod_j = (const float*)d_in[3];
  const float* Anorm = (const float*)d_in[4];
  const float* chW0  = (const float*)d_in[5];
  const float* chb0  = (const float*)d_in[6];
  const float* chW1  = (const float*)d_in[7];
  const float* mixW  = (const float*)d_in[8];
  const float* mixb  = (const float*)d_in[9];
  const float* Wih   = (const float*)d_in[10];
  const float* Whh   = (const float*)d_in[11];
  const float* bih   = (const float*)d_in[12];
  const float* bhh   = (const float*)d_in[13];
  const float* outW  = (const float*)d_in[14];
  const float* outbp = (const float*)d_in[15];
  const float* jamW  = (const float*)d_in[16];
  const float* jambp = (const float*)d_in[17];
  const float* fW1   = (const float*)d_in[18];
  const float* fb1   = (const float*)d_in[19];
  const float* fW2   = (const float*)d_in[20];
  const float* fb2   = (const float*)d_in[21];
  const float* qkvW  = (const float*)d_in[22];
  const float* qkvb  = (const float*)d_in[23];
  const float* oW    = (const float*)d_in[24];
  const float* ob    = (const float*)d_in[25];
  const float* ln1g  = (const float*)d_in[26];
  const float* ln1b  = (const float*)d_in[27];
  const float* f1W   = (const float*)d_in[28];
  const float* f1b   = (const float*)d_in[29];
  const float* f2W   = (const float*)d_in[30];
  const float* f2b   = (const float*)d_in[31];
  const float* ln2g  = (const float*)d_in[32];
  const float* ln2b  = (const float*)d_in[33];
  const float* prW   = (const float*)d_in[34];
  const float* prb   = (const float*)d_in[35];
  float* out = (float*)d_out;

  float* ws = (float*)d_ws;
  size_t off = 0;
  auto take = [&](size_t n)->float*{ float* p = ws + off; off += (n + 63) & ~(size_t)63; return p; };
  int*   slots = (int*)take(4096);   // 154 flags x 64B stride
  float* W0T  = take((size_t)2*67*256);
  float* W1T  = take((size_t)2*67*256);
  float* WihT = take((size_t)2*66*192);
  float* WhhT = take((size_t)2*64*192);
  int*   spcnt = (int*)take(320);
  int*   spidx = (int*)take((size_t)NN*NN);
  float* spval = take((size_t)NN*NN);
  float* AF    = take((size_t)3*NN*TT);
  float* HSEQ  = take((size_t)2*257*NN*64);
  float* X0    = take((size_t)NROW*64);
  float* XBUF  = take((size_t)2*NROW*64);   // per-enhancer
  float* OBUF  = take((size_t)2*NROW*64);   // per-enhancer
  u16* WHI = (u16*)take(((size_t)NWTOT + 1)/2);
  u16* WLO = (u16*)take(((size_t)NWTOT + 1)/2);
  (void)ws_size; (void)in_sizes; (void)n_in; (void)out_size;

  const size_t NQKV = (size_t)6*192*64;
  const size_t NO   = (size_t)6*64*64;
  const size_t NF1  = (size_t)6*256*64;
  const size_t NF2  = (size_t)6*64*256;

  hipMemsetAsync(slots, 0, 4096*sizeof(int), stream);
  hipMemsetAsync(HSEQ, 0, (size_t)NN*64*sizeof(float), stream);                     // h0 fwd
  hipMemsetAsync(HSEQ + (size_t)257*NN*64, 0, (size_t)NN*64*sizeof(float), stream); // h0 bwd

  k_sparse<<<dim3((NN+63)/64), dim3(64), 0, stream>>>(Anorm, spcnt, spidx, spval);
  k_tr_cheb<<<dim3(134), dim3(256), 0, stream>>>(chW0, chW1, W0T, W1T);
  k_tr_gru<<<dim3(99), dim3(256), 0, stream>>>(Wih, Whh, WihT, WhhT);
  k_af<<<dim3(NN,3), dim3(256), 0, stream>>>(m_seq, tod_f, tod_j, spcnt, spidx, spval, AF);
  k_split<<<dim3((int)((NQKV+255)/256)), dim3(256), 0, stream>>>(qkvW, WHI, WLO, (int)NQKV);
  k_split<<<dim3((int)((NO+255)/256)), dim3(256), 0, stream>>>(oW, WHI+OFF_O, WLO+OFF_O, (int)NO);
  k_split<<<dim3((int)((NF1+255)/256)), dim3(256), 0, stream>>>(f1W, WHI+OFF_F1, WLO+OFF_F1, (int)NF1);
  k_split<<<dim3((int)((NF2+255)/256)), dim3(256), 0, stream>>>(f2W, WHI+OFF_F2, WLO+OFF_F2, (int)NF2);

  k_scan<<<dim3(SCANB), dim3(256), 0, stream>>>(x_seq, m_seq, tod_f, tod_j, W0T, W1T,
      chb0, mixW, mixb, WihT, WhhT, bih, bhh,
      spcnt, spidx, spval, AF, HSEQ, slots);

  k_fusion<<<dim3(NROW/4), dim3(256), 0, stream>>>(HSEQ, outW, outbp, jamW, jambp,
      fW1, fb1, fW2, fb2, X0, out);

  for (int l = 0; l < 3; l++){
    k_qkattn<<<dim3(NN, 2), dim3(256), 0, stream>>>(X0, XBUF, l, WHI, WLO, qkvb, OBUF);
    k_oproj_ln<<<dim3(NROW/64, 2), dim3(256), 0, stream>>>(OBUF, X0, XBUF, l,
        WHI, WLO, ob, ln1g, ln1b);
    k_ffblock<<<dim3(NROW/64, 2), dim3(256), 0, stream>>>(XBUF, l, WHI, WLO,
        f1b, f2b, ln2g, ln2b);
  }
  k_proj_add<<<dim3(NROW/4, 2), dim3(256), 0, stream>>>(XBUF, prW, prb, out);
}

// Round 16
// 4341.459 us; speedup vs baseline: 1.0025x; 1.0025x over previous
//
#include <hip/hip_runtime.h>
#include <math.h>

// Problem constants
#define NN   307
#define TT   256
#define HHH  64
#define NROW (NN*TT)     // 78592
#define NBLK_D 77        // ceil(307/4) blocks per direction
#define SCANB  154       // total scan blocks (2 directions)

// split-weight store offsets (elements)
#define OFF_O  (6*192*64)
#define OFF_F1 (OFF_O + 6*64*64)
#define OFF_F2 (OFF_F1 + 6*256*64)
#define NWTOT  (OFF_F2 + 6*64*256)

typedef unsigned short u16;
typedef __attribute__((ext_vector_type(8))) short short8;
typedef __attribute__((ext_vector_type(4))) float f4;

// ---------------- helpers ----------------
__device__ __forceinline__ float wsum(float v){
#pragma unroll
  for (int off = 32; off > 0; off >>= 1) v += __shfl_xor(v, off, 64);
  return v;
}
__device__ __forceinline__ float wsum16(float v){
#pragma unroll
  for (int off = 8; off > 0; off >>= 1) v += __shfl_xor(v, off, 64);
  return v;
}
__device__ __forceinline__ float ftanh(float x){
  x = fminf(20.f, fmaxf(-20.f, x));
  float e = __expf(2.f*x);
  return (e - 1.f)/(e + 1.f);
}
__device__ __forceinline__ float fsigm(float x){ return 1.f/(1.f + __expf(-x)); }

__device__ __forceinline__ u16 f2bf(float x){
  unsigned u = __float_as_uint(x);
  u += 0x7fffu + ((u >> 16) & 1u);
  return (u16)(u >> 16);
}
__device__ __forceinline__ float bf2f(u16 h){
  return __uint_as_float((unsigned)h << 16);
}
__device__ __forceinline__ void split8(const float* xv, short8& hi, short8& lo){
  union { short8 v; u16 u[8]; } H, L;
#pragma unroll
  for (int j = 0; j < 8; j++){
    const float x = xv[j];
    const u16 h = f2bf(x);
    H.u[j] = h;
    L.u[j] = f2bf(x - bf2f(h));
  }
  hi = H.v; lo = L.v;
}
__device__ __forceinline__ short8 pack_hi8(const float* xv){
  union { short8 s; u16 u[8]; } pk;
#pragma unroll
  for (int j = 0; j < 8; j++) pk.u[j] = f2bf(xv[j]);
  return pk.s;
}

// ---------------- prep kernels ----------------
__global__ void k_sparse(const float* __restrict__ A, int* __restrict__ cnt,
                         int* __restrict__ idx, float* __restrict__ val){
  int n = blockIdx.x*64 + threadIdx.x;
  if (n >= NN) return;
  int c = 0;
  for (int m = 0; m < NN; m++){
    float a = A[n*NN + m];
    if (a != 0.f){ idx[n*NN + c] = m; val[n*NN + c] = a; c++; }
  }
  cnt[n] = c;
}

__global__ void k_tr_cheb(const float* __restrict__ W0, const float* __restrict__ W1,
                          float* __restrict__ W0T, float* __restrict__ W1T){
  int t = blockIdx.x*256 + threadIdx.x;
  if (t >= 2*67*256) return;
  int c = t & 255; int rest = t >> 8; int i = rest % 67; int d = rest / 67;
  int p = c >> 6, o = c & 63;
  int src = ((d*4 + p)*64 + o)*67 + i;
  W0T[t] = W0[src];
  W1T[t] = W1[src];
}

__global__ void k_tr_gru(const float* __restrict__ Wih, const float* __restrict__ Whh,
                         float* __restrict__ WihT, float* __restrict__ WhhT){
  int t = blockIdx.x*256 + threadIdx.x;
  if (t < 2*66*192){
    int j = t % 192; int rest = t / 192; int i = rest % 66; int d = rest / 66;
    WihT[t] = Wih[(d*192 + j)*66 + i];
  }
  if (t < 2*64*192){
    int j = t % 192; int rest = t / 192; int i = rest % 64; int d = rest / 64;
    WhhT[t] = Whh[(d*192 + j)*64 + i];
  }
}

__global__ void k_af(const float* __restrict__ mseq, const float* __restrict__ tfr,
                     const float* __restrict__ tjm, const int* __restrict__ cnt,
                     const int* __restrict__ idx, const float* __restrict__ val,
                     float* __restrict__ AF){
  int n = blockIdx.x, c = blockIdx.y, t = threadIdx.x;
  const float* feat = (c == 0) ? mseq : (c == 1) ? tfr : tjm;
  float acc = 0.f; int k = cnt[n];
  for (int s = 0; s < k; s++) acc += val[n*NN + s] * feat[idx[n*NN + s]*TT + t];
  AF[((size_t)c*NN + n)*TT + t] = acc;
}

__global__ void k_split(const float* __restrict__ src, u16* __restrict__ hi,
                        u16* __restrict__ lo, int n){
  int i = blockIdx.x*256 + threadIdx.x;
  if (i >= n) return;
  const float x = src[i];
  const u16 h = f2bf(x);
  hi[i] = h;
  lo[i] = f2bf(x - bf2f(h));
}

// --- recurrent scan: dataflow sync (round-15 structure, converged ~12.2us/step) ---
__global__ __launch_bounds__(256, 1)
void k_scan(const float* __restrict__ xseq, const float* __restrict__ mseq,
            const float* __restrict__ tfr, const float* __restrict__ tjm,
            const float* __restrict__ W0T, const float* __restrict__ W1T,
            const float* __restrict__ b0g,
            const float* __restrict__ mixW, const float* __restrict__ mixb,
            const float* __restrict__ WihT, const float* __restrict__ WhhT,
            const float* __restrict__ bih, const float* __restrict__ bhh,
            const int* __restrict__ spcnt, const int* __restrict__ spidx,
            const float* __restrict__ spval, const float* __restrict__ AF,
            float* __restrict__ Hseq, int* __restrict__ slots)
{
  const int tid = threadIdx.x;
  const int bid = blockIdx.x;
  const int d   = bid / NBLK_D;
  const int n0  = (bid % NBLK_D) * 4;
  const int lane = tid & 63;
  const int wid  = tid >> 6;

  __shared__ __align__(16) float hsT[64][4];
  __shared__ __align__(16) float amsT[68][4];
  __shared__ __align__(16) float msgsT[64][4];
  __shared__ float malls[256][5];
  __shared__ float gis[4][192];
  __shared__ float ghs[4][192];
  __shared__ float mixs[4][4];
  __shared__ float xss[4], mss[4], tfs[4], tjs[4];
  __shared__ int   s_idx[4][320];
  __shared__ float s_val[4][320];
  __shared__ int   s_cnt[4];
  __shared__ int   s_need[NBLK_D];

  float w0r[67], w1r[67];
#pragma unroll
  for (int i = 0; i < 67; i++){
    w0r[i] = W0T[(d*67 + i)*256 + tid];
    w1r[i] = W1T[(d*67 + i)*256 + tid];
  }
  const float b0r = b0g[d*256 + tid];
  float wih_r[64], whh_r[64];
  float wih64 = 0.f, wih65 = 0.f, bih_r = 0.f, bhh_r = 0.f;
  if (tid < 192){
#pragma unroll
    for (int i = 0; i < 64; i++){
      whh_r[i] = WhhT[(d*64 + i)*192 + tid];
      wih_r[i] = WihT[(d*66 + i)*192 + tid];
    }
    wih64 = WihT[(d*66 + 64)*192 + tid];
    wih65 = WihT[(d*66 + 65)*192 + tid];
    bih_r = bih[d*192 + tid];
    bhh_r = bhh[d*192 + tid];
  }
  float mixw_r[4];
#pragma unroll
  for (int p = 0; p < 4; p++) mixw_r[p] = mixW[(d*4 + p)*64 + lane];
  const float mixb0 = mixb[d*4+0], mixb1 = mixb[d*4+1], mixb2 = mixb[d*4+2], mixb3 = mixb[d*4+3];

  for (int i = tid; i < NBLK_D; i += 256) s_need[i] = 0;
  __syncthreads();
  for (int r = 0; r < 4; r++){
    const int n = min(n0 + r, NN-1);
    const int cc = spcnt[n];
    const int ccp = (cc + 15) & ~15;
    if (tid == 0) s_cnt[r] = ccp;
    for (int s = tid; s < ccp; s += 256){
      const int m = (s < cc) ? spidx[n*NN + s] : 0;
      s_idx[r][s] = m;
      s_val[r][s] = (s < cc) ? spval[n*NN + s] : 0.f;
      s_need[m >> 2] = 1;
    }
  }
  hsT[lane][wid] = 0.f;
  __syncthreads();
  const bool need0 = (lane < NBLK_D) && (s_need[lane] != 0);
  const bool need1 = (lane + 64 < NBLK_D) && (s_need[lane + 64] != 0);

#pragma unroll 1
  for (int k = 0; k < TT; k++){
    const int ts = (d == 0) ? k : (TT-1 - k);
    if (tid < 4){
      const int r = tid; const int n = min(n0 + r, NN-1);
      const float mv = mseq[n*TT + ts];
      mss[r] = mv; tfs[r] = tfr[n*TT + ts]; tjs[r] = tjm[n*TT + ts];
      xss[r] = xseq[n*TT + ts];
      amsT[64][r] = AF[(0*NN + n)*TT + ts];
      amsT[65][r] = AF[(1*NN + n)*TT + ts];
      amsT[66][r] = AF[(2*NN + n)*TT + ts];
    }
    {
      const int r = wid;
      const float hv = hsT[lane][r];
      float l0 = wsum(hv * mixw_r[0]) + mixb0;
      float l1 = wsum(hv * mixw_r[1]) + mixb1;
      float l2 = wsum(hv * mixw_r[2]) + mixb2;
      float l3 = wsum(hv * mixw_r[3]) + mixb3;
      const float mx = fmaxf(fmaxf(l0,l1), fmaxf(l2,l3));
      const float e0 = __expf(l0-mx), e1 = __expf(l1-mx), e2 = __expf(l2-mx), e3 = __expf(l3-mx);
      const float inv = 1.f/(e0+e1+e2+e3);
      if (lane == 0){
        mixs[0][r] = e0*inv; mixs[1][r] = e1*inv; mixs[2][r] = e2*inv; mixs[3][r] = e3*inv;
      }
    }
    __syncthreads();
    {
      float a0 = b0r, a1 = b0r, a2 = b0r, a3 = b0r;
#pragma unroll
      for (int i = 0; i < 64; i++){
        const float4 h4 = *(const float4*)&hsT[i][0];
        const float w = w0r[i];
        a0 += h4.x*w; a1 += h4.y*w; a2 += h4.z*w; a3 += h4.w*w;
      }
      a0 += mss[0]*w0r[64] + tfs[0]*w0r[65] + tjs[0]*w0r[66];
      a1 += mss[1]*w0r[64] + tfs[1]*w0r[65] + tjs[1]*w0r[66];
      a2 += mss[2]*w0r[64] + tfs[2]*w0r[65] + tjs[2]*w0r[66];
      a3 += mss[3]*w0r[64] + tfs[3]*w0r[65] + tjs[3]*w0r[66];
      malls[tid][0] = a0; malls[tid][1] = a1; malls[tid][2] = a2; malls[tid][3] = a3;
    }
    if (tid < 192){
      float g0 = bhh_r, g1 = bhh_r, g2 = bhh_r, g3 = bhh_r;
#pragma unroll
      for (int i = 0; i < 64; i++){
        const float4 h4 = *(const float4*)&hsT[i][0];
        const float w = whh_r[i];
        g0 += h4.x*w; g1 += h4.y*w; g2 += h4.z*w; g3 += h4.w*w;
      }
      ghs[0][tid] = g0; ghs[1][tid] = g1; ghs[2][tid] = g2; ghs[3][tid] = g3;
      gis[0][tid] = bih_r + (xss[0]*mss[0])*wih64 + mss[0]*wih65;
      gis[1][tid] = bih_r + (xss[1]*mss[1])*wih64 + mss[1]*wih65;
      gis[2][tid] = bih_r + (xss[2]*mss[2])*wih64 + mss[2]*wih65;
      gis[3][tid] = bih_r + (xss[3]*mss[3])*wih64 + mss[3]*wih65;
    }
    if (k > 0 && tid < 64){
      const int* sl = slots + (size_t)d*NBLK_D*16;
      for (;;){
        const int va = need0
            ? __hip_atomic_load(&sl[lane*16], __ATOMIC_RELAXED, __HIP_MEMORY_SCOPE_AGENT)
            : 0x7fffffff;
        const int vb = need1
            ? __hip_atomic_load(&sl[(lane+64)*16], __ATOMIC_RELAXED, __HIP_MEMORY_SCOPE_AGENT)
            : 0x7fffffff;
        if (__all(min(va, vb) >= k)) break;
        __builtin_amdgcn_s_sleep(1);
      }
    }
    __syncthreads();
    {
      const float* Hprev = Hseq + (size_t)(d*257 + k)*NN*64;
      const int r = wid;
      const int ccp = s_cnt[r];
      float acc = 0.f;
      for (int s = 0; s < ccp; s += 16){
        float aV[16], hV[16];
#pragma unroll
        for (int u = 0; u < 16; u++){
          const int m = s_idx[r][s+u];
          aV[u] = s_val[r][s+u];
          hV[u] = __hip_atomic_load(&Hprev[(size_t)m*64 + lane],
                                    __ATOMIC_RELAXED, __HIP_MEMORY_SCOPE_AGENT);
        }
#pragma unroll
        for (int u = 0; u < 16; u++) acc += aV[u]*hV[u];
      }
      amsT[lane][r] = acc;
    }
    __syncthreads();
    {
      const int p = tid >> 6;
      float pa0 = malls[tid][0], pa1 = malls[tid][1], pa2 = malls[tid][2], pa3 = malls[tid][3];
#pragma unroll
      for (int i = 0; i < 67; i++){
        const float4 m4 = *(const float4*)&amsT[i][0];
        const float w = w1r[i];
        pa0 += m4.x*w; pa1 += m4.y*w; pa2 += m4.z*w; pa3 += m4.w*w;
      }
      malls[tid][0] = mixs[p][0]*ftanh(pa0);
      malls[tid][1] = mixs[p][1]*ftanh(pa1);
      malls[tid][2] = mixs[p][2]*ftanh(pa2);
      malls[tid][3] = mixs[p][3]*ftanh(pa3);
    }
    __syncthreads();
    msgsT[lane][wid] = malls[lane][wid] + malls[64+lane][wid] + malls[128+lane][wid] + malls[192+lane][wid];
    __syncthreads();
    if (tid < 192){
      float q0 = gis[0][tid], q1 = gis[1][tid], q2 = gis[2][tid], q3 = gis[3][tid];
#pragma unroll
      for (int i = 0; i < 64; i++){
        const float4 m4 = *(const float4*)&msgsT[i][0];
        const float w = wih_r[i];
        q0 += m4.x*w; q1 += m4.y*w; q2 += m4.z*w; q3 += m4.w*w;
      }
      gis[0][tid] = q0; gis[1][tid] = q1; gis[2][tid] = q2; gis[3][tid] = q3;
    }
    __syncthreads();
    {
      const int r = wid, o = lane;
      const float ir = gis[r][o], iz = gis[r][o+64], in_ = gis[r][o+128];
      const float hr = ghs[r][o], hz = ghs[r][o+64], hn = ghs[r][o+128];
      const float rr2 = fsigm(ir + hr);
      const float zz = fsigm(iz + hz);
      const float nnv = ftanh(in_ + rr2*hn);
      const float hold = hsT[o][r];
      const float h2 = (1.f - zz)*nnv + zz*hold + 0.1f*hold;
      hsT[o][r] = h2;
      const int n = n0 + r;
      if (n < NN)
        __hip_atomic_store(&Hseq[((size_t)(d*257 + k + 1)*NN + n)*64 + o], h2,
                           __ATOMIC_RELAXED, __HIP_MEMORY_SCOPE_AGENT);
    }
    __syncthreads();
    if (tid == 0)
      __hip_atomic_store(&slots[bid*16], k + 1, __ATOMIC_RELAXED, __HIP_MEMORY_SCOPE_AGENT);
  }
}

// ---------------- fusion: pred/jam from Hseq + fuse weights + pos-enc ----------------
__global__ __launch_bounds__(256)
void k_fusion(const float* __restrict__ Hseq,
              const float* __restrict__ outW, const float* __restrict__ outb,
              const float* __restrict__ jamW, const float* __restrict__ jamb,
              const float* __restrict__ fw1, const float* __restrict__ fb1,
              const float* __restrict__ fw2, const float* __restrict__ fb2,
              float* __restrict__ x0, float* __restrict__ outp)
{
  const int tid = threadIdx.x;
  const int rr = tid >> 6, lane = tid & 63;
  const int idx = blockIdx.x*4 + rr;
  const int n = idx >> 8, t = idx & 255;
  const float hf = Hseq[((size_t)(0*257 + t + 1)*NN + n)*64 + lane];
  const float hb = Hseq[((size_t)(257 + 256 - t)*NN + n)*64 + lane];
  const float pf = wsum(hf * outW[lane])      + outb[0];
  const float pb = wsum(hb * outW[64 + lane]) + outb[1];
  const float jf = wsum(hf * jamW[lane])      + jamb[0];
  const float jb = wsum(hb * jamW[64 + lane]) + jamb[1];
  const float hid = fmaxf(fw1[lane*2]*pf + fw1[lane*2+1]*pb + fb1[lane], 0.f);
  const float l0 = wsum(hid * fw2[lane]) + fb2[0];
  const float l1 = wsum(hid * fw2[64+lane]) + fb2[1];
  const float mx = fmaxf(l0,l1);
  const float e0 = __expf(l0-mx), e1 = __expf(l1-mx);
  const float inv = 1.f/(e0+e1);
  const float w0 = e0*inv, w1 = e1*inv;
  const int i2 = lane & ~1;
  const float dv = powf(10000.f, (float)i2 * (1.f/64.f));
  const float arg = (float)t / dv;
  const float pe = (lane & 1) ? cosf(arg) : sinf(arg);
  x0[(size_t)idx*64 + lane] = hf*w0 + hb*w1 + pe;
  if (lane == 0){
    outp[idx]        = 0.7f*(w0*pf + w1*pb);
    outp[NROW + idx] = 0.7f*(w0*jf + w1*jb);
  }
}

// ------- fused qkv + attention: block=(node, e), wave=head; no Xhi staging,
// ------- no block barriers (all LDS slices wave-private); X A-frags from global
__global__ __launch_bounds__(256)
void k_qkattn(const float* __restrict__ X0, const float* __restrict__ XBUF, int lyr,
              const u16* __restrict__ WHI, const u16* __restrict__ WLO,
              const float* __restrict__ qkvb_all, float* __restrict__ OBUF)
{
  __shared__ __align__(16) u16 Vt [4][16][280];
  __shared__ __align__(16) u16 Pst[4][16][264];
  __shared__ __align__(16) u16 Kscr[4][16][24];
  __shared__ __align__(16) u16 Qhs[4][16][24];
  __shared__ __align__(16) u16 Qls[4][16][24];
  const int n = blockIdx.x;
  const int e = blockIdx.y;
  const int el = e*3 + lyr;
  const float* X = (lyr == 0) ? X0 : (XBUF + (size_t)e*NROW*64);
  const u16* Whi = WHI + (size_t)el*192*64;
  const u16* Wlo = WLO + (size_t)el*192*64;
  const float* bias = qkvb_all + (size_t)el*192;
  float* O = OBUF + (size_t)e*NROW*64;
  const int tid = threadIdx.x;
  const int h = tid >> 6;
  const int l = tid & 63;
  const int m16 = l & 15, q = l >> 4;
  const float* xbase = X + (size_t)n*256*64;
  const short8 z8 = {0,0,0,0,0,0,0,0};

  short8 WqH[2], WqL[2], WkH[2], WkL[2], WvH[2], WvL[2];
#pragma unroll
  for (int kh = 0; kh < 2; kh++){
    const size_t rq = (size_t)(h*16 + m16)*64 + kh*32 + q*8;
    const size_t rk = (size_t)(64 + h*16 + m16)*64 + kh*32 + q*8;
    const size_t rv = (size_t)(128 + h*16 + m16)*64 + kh*32 + q*8;
    WqH[kh] = *(const short8*)&Whi[rq]; WqL[kh] = *(const short8*)&Wlo[rq];
    WkH[kh] = *(const short8*)&Whi[rk]; WkL[kh] = *(const short8*)&Wlo[rk];
    WvH[kh] = *(const short8*)&Whi[rv]; WvL[kh] = *(const short8*)&Wlo[rv];
  }
  const float qb = bias[h*16 + m16];
  const float kb = bias[64 + h*16 + m16];
  const float vb = bias[128 + h*16 + m16];

  // build K (register B-frags) and V^T (LDS), per key-tile; X read from global (L2)
  short8 Kb[16];
#pragma unroll 1
  for (int ct = 0; ct < 16; ct++){
    const float* xr = xbase + (size_t)(ct*16 + m16)*64;
    float xv0[8], xv1[8];
    *(float4*)&xv0[0] = *(const float4*)&xr[q*8];
    *(float4*)&xv0[4] = *(const float4*)&xr[q*8 + 4];
    *(float4*)&xv1[0] = *(const float4*)&xr[32 + q*8];
    *(float4*)&xv1[4] = *(const float4*)&xr[32 + q*8 + 4];
    const short8 Xa0 = pack_hi8(xv0);
    const short8 Xa1 = pack_hi8(xv1);
    f4 ka = {0.f,0.f,0.f,0.f}, va = {0.f,0.f,0.f,0.f};
    ka = __builtin_amdgcn_mfma_f32_16x16x32_bf16(Xa0, WkH[0], ka, 0, 0, 0);
    ka = __builtin_amdgcn_mfma_f32_16x16x32_bf16(Xa0, WkL[0], ka, 0, 0, 0);
    ka = __builtin_amdgcn_mfma_f32_16x16x32_bf16(Xa1, WkH[1], ka, 0, 0, 0);
    ka = __builtin_amdgcn_mfma_f32_16x16x32_bf16(Xa1, WkL[1], ka, 0, 0, 0);
    va = __builtin_amdgcn_mfma_f32_16x16x32_bf16(Xa0, WvH[0], va, 0, 0, 0);
    va = __builtin_amdgcn_mfma_f32_16x16x32_bf16(Xa0, WvL[0], va, 0, 0, 0);
    va = __builtin_amdgcn_mfma_f32_16x16x32_bf16(Xa1, WvH[1], va, 0, 0, 0);
    va = __builtin_amdgcn_mfma_f32_16x16x32_bf16(Xa1, WvL[1], va, 0, 0, 0);
#pragma unroll
    for (int r = 0; r < 4; r++){
      Kscr[h][q*4 + r][m16] = f2bf(ka[r] + kb);
      Vt[h][m16][ct*16 + q*4 + r] = f2bf(va[r] + vb);
    }
    Kb[ct] = (q < 2) ? *(const short8*)&Kscr[h][m16][q*8] : z8;
  }

#pragma unroll 1
  for (int c = 0; c < 16; c++){
    const float* xr = xbase + (size_t)(c*16 + m16)*64;
    float xv0[8], xv1[8];
    *(float4*)&xv0[0] = *(const float4*)&xr[q*8];
    *(float4*)&xv0[4] = *(const float4*)&xr[q*8 + 4];
    *(float4*)&xv1[0] = *(const float4*)&xr[32 + q*8];
    *(float4*)&xv1[4] = *(const float4*)&xr[32 + q*8 + 4];
    const short8 Xa0 = pack_hi8(xv0);
    const short8 Xa1 = pack_hi8(xv1);
    f4 qa = {0.f,0.f,0.f,0.f};
    qa = __builtin_amdgcn_mfma_f32_16x16x32_bf16(Xa0, WqH[0], qa, 0, 0, 0);
    qa = __builtin_amdgcn_mfma_f32_16x16x32_bf16(Xa0, WqL[0], qa, 0, 0, 0);
    qa = __builtin_amdgcn_mfma_f32_16x16x32_bf16(Xa1, WqH[1], qa, 0, 0, 0);
    qa = __builtin_amdgcn_mfma_f32_16x16x32_bf16(Xa1, WqL[1], qa, 0, 0, 0);
#pragma unroll
    for (int r = 0; r < 4; r++){
      const float qv = (qa[r] + qb) * 0.25f;
      const u16 hh = f2bf(qv);
      Qhs[h][q*4 + r][m16] = hh;
      Qls[h][q*4 + r][m16] = f2bf(qv - bf2f(hh));
    }
    short8 Qh = z8, Ql = z8;
    if (q < 2){
      Qh = *(const short8*)&Qhs[h][m16][q*8];
      Ql = *(const short8*)&Qls[h][m16][q*8];
    }
    float rs[4] = {0.f, 0.f, 0.f, 0.f};
#pragma unroll
    for (int ct = 0; ct < 16; ct++){
      f4 s = {0.f,0.f,0.f,0.f};
      s = __builtin_amdgcn_mfma_f32_16x16x32_bf16(Qh, Kb[ct], s, 0, 0, 0);
      s = __builtin_amdgcn_mfma_f32_16x16x32_bf16(Ql, Kb[ct], s, 0, 0, 0);
#pragma unroll
      for (int r = 0; r < 4; r++){
        const float p = __expf(s[r]);
        rs[r] += p;
        Pst[h][q*4 + r][ct*16 + m16] = f2bf(p);
      }
    }
#pragma unroll
    for (int r = 0; r < 4; r++) rs[r] = wsum16(rs[r]);
    f4 acc = {0.f,0.f,0.f,0.f};
#pragma unroll
    for (int kt = 0; kt < 8; kt++){
      const short8 Pa = *(const short8*)&Pst[h][m16][kt*32 + q*8];
      const short8 Vb = *(const short8*)&Vt[h][m16][kt*32 + q*8];
      acc = __builtin_amdgcn_mfma_f32_16x16x32_bf16(Pa, Vb, acc, 0, 0, 0);
    }
#pragma unroll
    for (int r = 0; r < 4; r++){
      O[((size_t)n*256 + c*16 + q*4 + r)*64 + h*16 + m16] = acc[r] / rs[r];
    }
  }
}

// ------- fused MLP: oproj + res + LN1 + FF1 + FF2 + res + LN2 -------
// block=(64-row tile, e); all LDS transforms stay within each wave's 16-row
// band (D-layout rows w*16+q*4+r, A-frag rows w*16+m16) => no block barriers.
__global__ __launch_bounds__(256)
void k_mlp(const float* __restrict__ OBUF, const float* __restrict__ X0,
           float* __restrict__ XBUF, int lyr,
           const u16* __restrict__ WHI, const u16* __restrict__ WLO,
           const float* __restrict__ ob_all,
           const float* __restrict__ g1_all, const float* __restrict__ b1ln_all,
           const float* __restrict__ f1b_all, const float* __restrict__ f2b_all,
           const float* __restrict__ g2_all, const float* __restrict__ b2ln_all)
{
  __shared__ __align__(16) u16 Xh[64][72];
  __shared__ __align__(16) u16 Xl[64][72];
  __shared__ __align__(16) u16 Hs[64][280];
  const int e = blockIdx.y;
  const int el = e*3 + lyr;
  const float* Oin = OBUF + (size_t)e*NROW*64;
  const float* Xres = (lyr == 0) ? X0 : (XBUF + (size_t)e*NROW*64);
  float* Y = XBUF + (size_t)e*NROW*64;
  const u16* oWhi = WHI + OFF_O + (size_t)el*64*64;
  const u16* oWlo = WLO + OFF_O + (size_t)el*64*64;
  const u16* W1hi = WHI + OFF_F1 + (size_t)el*256*64;
  const u16* W1lo = WLO + OFF_F1 + (size_t)el*256*64;
  const u16* W2hi = WHI + OFF_F2 + (size_t)el*64*256;
  const u16* W2lo = WLO + OFF_F2 + (size_t)el*64*256;
  const float* obb = ob_all + (size_t)el*64;
  const float* g1 = g1_all + (size_t)el*64;
  const float* b1ln = b1ln_all + (size_t)el*64;
  const float* f1b = f1b_all + (size_t)el*256;
  const float* f2b = f2b_all + (size_t)el*64;
  const float* g2 = g2_all + (size_t)el*64;
  const float* b2ln = b2ln_all + (size_t)el*64;
  const int tid = threadIdx.x;
  const int w = tid >> 6, l = tid & 63;
  const int m16 = l & 15, q = l >> 4;
  const int row = blockIdx.x*64 + w*16 + m16;
  const int rbase = blockIdx.x*64 + w*16 + q*4;

  // ---- stage A: oproj (split-bf16 MFMA) + bias + residual + LN1 ----
  short8 Ah[2], Al[2];
#pragma unroll
  for (int kh = 0; kh < 2; kh++){
    float xv[8];
    *(float4*)&xv[0] = *(const float4*)&Oin[(size_t)row*64 + kh*32 + q*8];
    *(float4*)&xv[4] = *(const float4*)&Oin[(size_t)row*64 + kh*32 + q*8 + 4];
    split8(xv, Ah[kh], Al[kh]);
  }
  f4 acc[4];
#pragma unroll
  for (int nt = 0; nt < 4; nt++){
    acc[nt] = (f4){0.f, 0.f, 0.f, 0.f};
    const int n = nt*16 + m16;
#pragma unroll
    for (int kh = 0; kh < 2; kh++){
      const short8 Bh = *(const short8*)&oWhi[(size_t)n*64 + kh*32 + q*8];
      const short8 Bl = *(const short8*)&oWlo[(size_t)n*64 + kh*32 + q*8];
      acc[nt] = __builtin_amdgcn_mfma_f32_16x16x32_bf16(Ah[kh], Bh, acc[nt], 0, 0, 0);
      acc[nt] = __builtin_amdgcn_mfma_f32_16x16x32_bf16(Ah[kh], Bl, acc[nt], 0, 0, 0);
      acc[nt] = __builtin_amdgcn_mfma_f32_16x16x32_bf16(Al[kh], Bh, acc[nt], 0, 0, 0);
    }
  }
  float vv[4][4];   // LN1 output, D-layout (r, nt) — kept as FF2 residual
#pragma unroll
  for (int r = 0; r < 4; r++){
    float s = 0.f;
#pragma unroll
    for (int nt = 0; nt < 4; nt++){
      const int col = nt*16 + m16;
      vv[r][nt] = acc[nt][r] + obb[col] + Xres[(size_t)(rbase + r)*64 + col];
      s += vv[r][nt];
    }
    const float mu = wsum16(s) * (1.f/64.f);
    float vs = 0.f;
#pragma unroll
    for (int nt = 0; nt < 4; nt++){ vv[r][nt] -= mu; vs += vv[r][nt]*vv[r][nt]; }
    const float rstd = rsqrtf(wsum16(vs) * (1.f/64.f) + 1e-5f);
#pragma unroll
    for (int nt = 0; nt < 4; nt++){
      const int col = nt*16 + m16;
      vv[r][nt] = vv[r][nt] * rstd * g1[col] + b1ln[col];
      const u16 hh = f2bf(vv[r][nt]);
      Xh[w*16 + q*4 + r][col] = hh;
      Xl[w*16 + q*4 + r][col] = f2bf(vv[r][nt] - bf2f(hh));
    }
  }
  // wave-private LDS: ds ordering within wave is automatic (lgkmcnt)
  // ---- stage B: FF1 = relu(X @ W1^T + b1) -> Hs (bf16 hi) ----
  short8 Xa_h[2], Xa_l[2];
#pragma unroll
  for (int kh = 0; kh < 2; kh++){
    Xa_h[kh] = *(const short8*)&Xh[w*16 + m16][kh*32 + q*8];
    Xa_l[kh] = *(const short8*)&Xl[w*16 + m16][kh*32 + q*8];
  }
  for (int nt = 0; nt < 16; nt++){
    const int n = nt*16 + m16;
    f4 a1 = {0.f, 0.f, 0.f, 0.f};
#pragma unroll
    for (int kh = 0; kh < 2; kh++){
      const short8 Bh = *(const short8*)&W1hi[(size_t)n*64 + kh*32 + q*8];
      const short8 Bl = *(const short8*)&W1lo[(size_t)n*64 + kh*32 + q*8];
      a1 = __builtin_amdgcn_mfma_f32_16x16x32_bf16(Xa_h[kh], Bh, a1, 0, 0, 0);
      a1 = __builtin_amdgcn_mfma_f32_16x16x32_bf16(Xa_h[kh], Bl, a1, 0, 0, 0);
      a1 = __builtin_amdgcn_mfma_f32_16x16x32_bf16(Xa_l[kh], Bh, a1, 0, 0, 0);
    }
    const float bb = f1b[n];
#pragma unroll
    for (int r = 0; r < 4; r++){
      const float h = fmaxf(a1[r] + bb, 0.f);
      Hs[w*16 + q*4 + r][n] = f2bf(h);
    }
  }
  // ---- stage C: FF2 = H @ W2^T + b2 + residual(vv) -> LN2 -> Y ----
  f4 acc2[4];
#pragma unroll
  for (int nt = 0; nt < 4; nt++) acc2[nt] = (f4){0.f, 0.f, 0.f, 0.f};
#pragma unroll 1
  for (int kh = 0; kh < 8; kh++){
    const short8 Ahh = *(const short8*)&Hs[w*16 + m16][kh*32 + q*8];
#pragma unroll
    for (int nt = 0; nt < 4; nt++){
      const int n = nt*16 + m16;
      const short8 Bh = *(const short8*)&W2hi[(size_t)n*256 + kh*32 + q*8];
      const short8 Bl = *(const short8*)&W2lo[(size_t)n*256 + kh*32 + q*8];
      acc2[nt] = __builtin_amdgcn_mfma_f32_16x16x32_bf16(Ahh, Bh, acc2[nt], 0, 0, 0);
      acc2[nt] = __builtin_amdgcn_mfma_f32_16x16x32_bf16(Ahh, Bl, acc2[nt], 0, 0, 0);
    }
  }
#pragma unroll
  for (int r = 0; r < 4; r++){
    float v[4]; float s = 0.f;
#pragma unroll
    for (int nt = 0; nt < 4; nt++){
      const int col = nt*16 + m16;
      v[nt] = acc2[nt][r] + f2b[col] + vv[r][nt];
      s += v[nt];
    }
    const float mu = wsum16(s) * (1.f/64.f);
    float vs = 0.f;
#pragma unroll
    for (int nt = 0; nt < 4; nt++){ v[nt] -= mu; vs += v[nt]*v[nt]; }
    const float rstd = rsqrtf(wsum16(vs) * (1.f/64.f) + 1e-5f);
#pragma unroll
    for (int nt = 0; nt < 4; nt++){
      const int col = nt*16 + m16;
      Y[(size_t)(rbase + r)*64 + col] = v[nt] * rstd * g2[col] + b2ln[col];
    }
  }
}

// ---------------- final projection: block=(tile, e) ----------------
__global__ __launch_bounds__(256)
void k_proj_add(const float* __restrict__ XBUF, const float* __restrict__ prW,
                const float* __restrict__ prb, float* __restrict__ out)
{
  const int e = blockIdx.y;
  const float* X = XBUF + (size_t)e*NROW*64;
  const float* pW = prW + (size_t)e*64;
  float* outp = out + (size_t)e*NROW;
  const int tid = threadIdx.x;
  const int r = tid >> 6, lane = tid & 63;
  const size_t row = (size_t)blockIdx.x*4 + r;
  const float v = X[row*64 + lane] * pW[lane];
  const float s = wsum(v);
  if (lane == 0) outp[row] += 0.3f*(s + prb[e]);
}

// ---------------- host launcher ----------------
extern "C" void kernel_launch(void* const* d_in, const int* in_sizes, int n_in,
                              void* d_out, int out_size, void* d_ws, size_t ws_size,
                              hipStream_t stream)
{
  const float* x_seq = (const float*)d_in[0];
  const float* m_seq = (const float*)d_in[1];
  const float* tod_f = (const float*)d_in[2];
  const float* tod_j = (const float*)d_in[3];
  const float* Anorm = (const float*)d_in[4];
  const float* chW0  = (const float*)d_in[5];
  const float* chb0  = (const float*)d_in[6];
  const float* chW1  = (const float*)d_in[7];
  const float* mixW  = (const float*)d_in[8];
  const float* mixb  = (const float*)d_in[9];
  const float* Wih   = (const float*)d_in[10];
  const float* Whh   = (const float*)d_in[11];
  const float* bih   = (const float*)d_in[12];
  const float* bhh   = (const float*)d_in[13];
  const float* outW  = (const float*)d_in[14];
  const float* outbp = (const float*)d_in[15];
  const float* jamW  = (const float*)d_in[16];
  const float* jambp = (const float*)d_in[17];
  const float* fW1   = (const float*)d_in[18];
  const float* fb1   = (const float*)d_in[19];
  const float* fW2   = (const float*)d_in[20];
  const float* fb2   = (const float*)d_in[21];
  const float* qkvW  = (const float*)d_in[22];
  const float* qkvb  = (const float*)d_in[23];
  const float* oW    = (const float*)d_in[24];
  const float* ob    = (const float*)d_in[25];
  const float* ln1g  = (const float*)d_in[26];
  const float* ln1b  = (const float*)d_in[27];
  const float* f1W   = (const float*)d_in[28];
  const float* f1b   = (const float*)d_in[29];
  const float* f2W   = (const float*)d_in[30];
  const float* f2b   = (const float*)d_in[31];
  const float* ln2g  = (const float*)d_in[32];
  const float* ln2b  = (const float*)d_in[33];
  const float* prW   = (const float*)d_in[34];
  const float* prb   = (const float*)d_in[35];
  float* out = (float*)d_out;

  float* ws = (float*)d_ws;
  size_t off = 0;
  auto take = [&](size_t n)->float*{ float* p = ws + off; off += (n + 63) & ~(size_t)63; return p; };
  int*   slots = (int*)take(4096);   // 154 flags x 64B stride
  float* W0T  = take((size_t)2*67*256);
  float* W1T  = take((size_t)2*67*256);
  float* WihT = take((size_t)2*66*192);
  float* WhhT = take((size_t)2*64*192);
  int*   spcnt = (int*)take(320);
  int*   spidx = (int*)take((size_t)NN*NN);
  float* spval = take((size_t)NN*NN);
  float* AF    = take((size_t)3*NN*TT);
  float* HSEQ  = take((size_t)2*257*NN*64);
  float* X0    = take((size_t)NROW*64);
  float* XBUF  = take((size_t)2*NROW*64);   // per-enhancer
  float* OBUF  = take((size_t)2*NROW*64);   // per-enhancer
  u16* WHI = (u16*)take(((size_t)NWTOT + 1)/2);
  u16* WLO = (u16*)take(((size_t)NWTOT + 1)/2);
  (void)ws_size; (void)in_sizes; (void)n_in; (void)out_size;

  const size_t NQKV = (size_t)6*192*64;
  const size_t NO   = (size_t)6*64*64;
  const size_t NF1  = (size_t)6*256*64;
  const size_t NF2  = (size_t)6*64*256;

  hipMemsetAsync(slots, 0, 4096*sizeof(int), stream);
  hipMemsetAsync(HSEQ, 0, (size_t)NN*64*sizeof(float), stream);                     // h0 fwd
  hipMemsetAsync(HSEQ + (size_t)257*NN*64, 0, (size_t)NN*64*sizeof(float), stream); // h0 bwd

  k_sparse<<<dim3((NN+63)/64), dim3(64), 0, stream>>>(Anorm, spcnt, spidx, spval);
  k_tr_cheb<<<dim3(134), dim3(256), 0, stream>>>(chW0, chW1, W0T, W1T);
  k_tr_gru<<<dim3(99), dim3(256), 0, stream>>>(Wih, Whh, WihT, WhhT);
  k_af<<<dim3(NN,3), dim3(256), 0, stream>>>(m_seq, tod_f, tod_j, spcnt, spidx, spval, AF);
  k_split<<<dim3((int)((NQKV+255)/256)), dim3(256), 0, stream>>>(qkvW, WHI, WLO, (int)NQKV);
  k_split<<<dim3((int)((NO+255)/256)), dim3(256), 0, stream>>>(oW, WHI+OFF_O, WLO+OFF_O, (int)NO);
  k_split<<<dim3((int)((NF1+255)/256)), dim3(256), 0, stream>>>(f1W, WHI+OFF_F1, WLO+OFF_F1, (int)NF1);
  k_split<<<dim3((int)((NF2+255)/256)), dim3(256), 0, stream>>>(f2W, WHI+OFF_F2, WLO+OFF_F2, (int)NF2);

  k_scan<<<dim3(SCANB), dim3(256), 0, stream>>>(x_seq, m_seq, tod_f, tod_j, W0T, W1T,
      chb0, mixW, mixb, WihT, WhhT, bih, bhh,
      spcnt, spidx, spval, AF, HSEQ, slots);

  k_fusion<<<dim3(NROW/4), dim3(256), 0, stream>>>(HSEQ, outW, outbp, jamW, jambp,
      fW1, fb1, fW2, fb2, X0, out);

  for (int l = 0; l < 3; l++){
    k_qkattn<<<dim3(NN, 2), dim3(256), 0, stream>>>(X0, XBUF, l, WHI, WLO, qkvb, OBUF);
    k_mlp<<<dim3(NROW/64, 2), dim3(256), 0, stream>>>(OBUF, X0, XBUF, l,
        WHI, WLO, ob, ln1g, ln1b, f1b, f2b, ln2g, ln2b);
  }
  k_proj_add<<<dim3(NROW/4, 2), dim3(256), 0, stream>>>(XBUF, prW, prb, out);
}